// Round 1
// baseline (430.669 us; speedup 1.0000x reference)
//
#include <hip/hip_runtime.h>
#include <hip/hip_bf16.h>

typedef __bf16 bf16_t;
typedef __bf16 bf16x8 __attribute__((ext_vector_type(8)));
typedef __bf16 bf16x4 __attribute__((ext_vector_type(4)));
typedef float  f32x4  __attribute__((ext_vector_type(4)));

#define LDS_DST(p) ((__attribute__((address_space(3))) void*)(p))
#define GLB_SRC(p) ((const __attribute__((address_space(1))) void*)(p))

#define BM 128
#define BN 128
#define BK 64

// ---------------- fp32 -> bf16 convert (vectorized: float4 in, 4x bf16 out) ----
__global__ void __launch_bounds__(256)
f32_to_bf16_kernel(const float* __restrict__ in, bf16_t* __restrict__ out, int n4) {
  int i = blockIdx.x * 256 + threadIdx.x;
  if (i < n4) {
    const float4 v = reinterpret_cast<const float4*>(in)[i];
    bf16x4 o;
    o[0] = (bf16_t)v.x; o[1] = (bf16_t)v.y; o[2] = (bf16_t)v.z; o[3] = (bf16_t)v.w;
    reinterpret_cast<bf16x4*>(out)[i] = o;
  }
}

// ---------------- bf16 transpose: in [z][R][C] -> out [z][C][R] ----------------
__global__ void __launch_bounds__(256)
transpose_bf16_kernel(const bf16_t* __restrict__ in, bf16_t* __restrict__ out,
                      int R, int C) {
  __shared__ bf16_t tile[64][72];  // +8 pad: write-phase column reads spread banks
  const long base = (long)blockIdx.z * R * C;
  const bf16_t* ib = in + base;
  bf16_t* ob = out + base;
  const int r0 = blockIdx.x * 64, c0 = blockIdx.y * 64;
  const int tid = threadIdx.x;
  const int rr = tid >> 3, cg = tid & 7;
#pragma unroll
  for (int p = 0; p < 2; ++p) {
    int row = p * 32 + rr;
    bf16x8 v = *reinterpret_cast<const bf16x8*>(ib + (long)(r0 + row) * C + c0 + cg * 8);
    *reinterpret_cast<bf16x8*>(&tile[row][cg * 8]) = v;
  }
  __syncthreads();
#pragma unroll
  for (int p = 0; p < 2; ++p) {
    int c = p * 32 + rr;
    bf16x8 v;
#pragma unroll
    for (int i = 0; i < 8; ++i) v[i] = tile[cg * 8 + i][c];
    *reinterpret_cast<bf16x8*>(ob + (long)(c0 + c) * R + r0 + cg * 8) = v;
  }
}

// ---------------- GEMM, both operands K-contiguous ("B^T input") ---------------
// C[m][n] = sum_k A[m][k]*B[n][k]  (+bias / mask+sigmoid / plain fp32 per MODE)
// MODE 0: bf16 out = acc + bias[n]
// MODE 1: bf16 out = mask ? sigmoid(acc) : 0
// MODE 2: f32 out  = acc
// m97 structure: 128x128 tile, BK=64, 4 waves (2x2 of 64x64), 16x16x32 MFMA,
// global_load_lds width 16 with inverse-XOR-swizzled global source (rule #21),
// XOR-swizzled ds_read_b128 (T2-analog: byte ^= (row&7)<<4).
template <int MODE>
__global__ void __launch_bounds__(256)
gemm_bt_kernel(const bf16_t* __restrict__ A, const bf16_t* __restrict__ B,
               const float* __restrict__ bias, const int* __restrict__ mask,
               void* __restrict__ Cout, int M, int N, int K,
               long sA, long sB, long sC, long sMask) {
  __shared__ char smem[BM * BK * 2 + BN * BK * 2];  // 32 KiB
  char* As = smem;
  char* Bs = smem + BM * BK * 2;
  const int bz = blockIdx.z;
  const bf16_t* Ab = A + bz * sA;
  const bf16_t* Bb = B + bz * sB;
  const int bm = blockIdx.x * BM;
  const int bn = blockIdx.y * BN;
  const int tid = threadIdx.x;
  const int wave = tid >> 6, lane = tid & 63;
  const int wr = wave >> 1, wc = wave & 1;
  f32x4 acc[4][4] = {};

  for (int k0 = 0; k0 < K; k0 += BK) {
    // stage A tile [128][64] bf16 (16 KiB): 1024 chunks of 16B, linear LDS dest,
    // source column-group XORed so the swizzled read below sees the right data.
#pragma unroll
    for (int j = 0; j < 4; ++j) {
      int c = j * 256 + tid;
      int row = c >> 3;
      int cgs = (c & 7) ^ (row & 7);
      __builtin_amdgcn_global_load_lds(
          GLB_SRC(Ab + (long)(bm + row) * K + k0 + cgs * 8),
          LDS_DST(As + (j * 256 + wave * 64) * 16), 16, 0, 0);
    }
#pragma unroll
    for (int j = 0; j < 4; ++j) {
      int c = j * 256 + tid;
      int row = c >> 3;
      int cgs = (c & 7) ^ (row & 7);
      __builtin_amdgcn_global_load_lds(
          GLB_SRC(Bb + (long)(bn + row) * K + k0 + cgs * 8),
          LDS_DST(Bs + (j * 256 + wave * 64) * 16), 16, 0, 0);
    }
    __syncthreads();  // compiler emits vmcnt(0) drain before s_barrier

#pragma unroll
    for (int kk = 0; kk < 2; ++kk) {
      bf16x8 af[4], bfr[4];
#pragma unroll
      for (int t = 0; t < 4; ++t) {
        int ra = wr * 64 + t * 16 + (lane & 15);
        int ca = (kk * 64 + (lane >> 4) * 16) ^ ((ra & 7) << 4);
        af[t] = *reinterpret_cast<const bf16x8*>(As + ra * 128 + ca);
        int rb = wc * 64 + t * 16 + (lane & 15);
        int cb = (kk * 64 + (lane >> 4) * 16) ^ ((rb & 7) << 4);
        bfr[t] = *reinterpret_cast<const bf16x8*>(Bs + rb * 128 + cb);
      }
#pragma unroll
      for (int mt = 0; mt < 4; ++mt)
#pragma unroll
        for (int nt = 0; nt < 4; ++nt)
          acc[mt][nt] = __builtin_amdgcn_mfma_f32_16x16x32_bf16(
              af[mt], bfr[nt], acc[mt][nt], 0, 0, 0);
    }
    __syncthreads();
  }

  // epilogue: C/D layout col=lane&15, row=(lane>>4)*4+reg (m89-verified)
  const int col0 = bn + wc * 64;
  const int row0 = bm + wr * 64;
#pragma unroll
  for (int nt = 0; nt < 4; ++nt) {
    const int col = col0 + nt * 16 + (lane & 15);
    float bv = 0.f;
    if constexpr (MODE == 0) bv = bias[col];
#pragma unroll
    for (int mt = 0; mt < 4; ++mt) {
      const int rbase = row0 + mt * 16 + ((lane >> 4) << 2);
#pragma unroll
      for (int r = 0; r < 4; ++r) {
        const long off = (long)(rbase + r) * N + col;
        const float v = acc[mt][nt][r];
        if constexpr (MODE == 0) {
          ((bf16_t*)Cout + bz * sC)[off] = (bf16_t)(v + bv);
        } else if constexpr (MODE == 1) {
          const int mv = mask[bz * sMask + off];
          const float p = mv ? 1.f / (1.f + __expf(-v)) : 0.f;
          ((bf16_t*)Cout + bz * sC)[off] = (bf16_t)p;
        } else {
          ((float*)Cout + bz * sC)[off] = v;
        }
      }
    }
  }
}

extern "C" void kernel_launch(void* const* d_in, const int* in_sizes, int n_in,
                              void* d_out, int out_size, void* d_ws, size_t ws_size,
                              hipStream_t stream) {
  const float* queries = (const float*)d_in[0];
  const float* values  = (const float*)d_in[1];
  const int*   mask    = (const int*)d_in[2];
  const float* Wq = (const float*)d_in[3];
  const float* bq = (const float*)d_in[4];
  const float* Wk = (const float*)d_in[5];
  const float* bk = (const float*)d_in[6];
  const float* Wv = (const float*)d_in[7];
  const float* bv = (const float*)d_in[8];

  // B=8, L=2048, D=768. Workspace layout (bytes):
  char* ws = (char*)d_ws;
  bf16_t* qb  = (bf16_t*)(ws + 0);          // queries bf16   25165824
  bf16_t* vb  = (bf16_t*)(ws + 25165824);   // values bf16    25165824
  bf16_t* wqb = (bf16_t*)(ws + 50331648);   // Wq bf16         1179648
  bf16_t* wkb = (bf16_t*)(ws + 51511296);   // Wk bf16         1179648
  bf16_t* wvb = (bf16_t*)(ws + 52690944);   // Wv bf16         1179648
  bf16_t* qp  = (bf16_t*)(ws + 53870592);   // q_proj         25165824
  bf16_t* vp  = (bf16_t*)(ws + 79036416);   // v_proj         25165824
  bf16_t* kp  = (bf16_t*)(ws + 104202240);  // k_proj         25165824
  bf16_t* vpT = (bf16_t*)(ws + 129368064);  // v_proj^T       25165824
  bf16_t* P   = (bf16_t*)(ws + 154533888);  // sigmoid scores 67108864
  // total: 221642752 bytes

  const dim3 blk(256);

  // converts
  f32_to_bf16_kernel<<<12288, blk, 0, stream>>>(queries, qb, 3145728);
  f32_to_bf16_kernel<<<12288, blk, 0, stream>>>(values, vb, 3145728);
  f32_to_bf16_kernel<<<576, blk, 0, stream>>>(Wq, wqb, 147456);
  f32_to_bf16_kernel<<<576, blk, 0, stream>>>(Wk, wkb, 147456);
  f32_to_bf16_kernel<<<576, blk, 0, stream>>>(Wv, wvb, 147456);

  // projections: [16384,768] x W[768,768]^T + b -> bf16
  gemm_bt_kernel<0><<<dim3(128, 6, 1), blk, 0, stream>>>(
      qb, wqb, bq, nullptr, qp, 16384, 768, 768, 0, 0, 0, 0);
  gemm_bt_kernel<0><<<dim3(128, 6, 1), blk, 0, stream>>>(
      vb, wvb, bv, nullptr, vp, 16384, 768, 768, 0, 0, 0, 0);
  // NOTE faithful quirk: k = Linear_k(v_proj)
  gemm_bt_kernel<0><<<dim3(128, 6, 1), blk, 0, stream>>>(
      vp, wkb, bk, nullptr, kp, 16384, 768, 768, 0, 0, 0, 0);

  // v_proj [b][2048][768] -> v_projT [b][768][2048]
  transpose_bf16_kernel<<<dim3(32, 12, 8), blk, 0, stream>>>(vp, vpT, 2048, 768);

  // P = sigmoid(mask(q k^T)) : per batch [2048,2048], K=768
  gemm_bt_kernel<1><<<dim3(16, 16, 8), blk, 0, stream>>>(
      qp, kp, nullptr, mask, P, 2048, 2048, 768,
      (long)2048 * 768, (long)2048 * 768, (long)2048 * 2048, (long)2048 * 2048);

  // context = P v : per batch [2048,768], K=2048, fp32 out
  gemm_bt_kernel<2><<<dim3(16, 6, 8), blk, 0, stream>>>(
      P, vpT, nullptr, nullptr, d_out, 2048, 768, 2048,
      (long)2048 * 2048, (long)768 * 2048, (long)2048 * 768, 0);
}